// Round 9
// baseline (226.514 us; speedup 1.0000x reference)
//
#include <hip/hip_runtime.h>
#include <math.h>

#define BB 2
#define SS 2048
#define DD 1024
#define HH 16
#define HDIM 64

#define SCL 0.18033688f   // (1/sqrt(64)) * log2(e), folded into Q at QKV epilogue
#define FM  12.0f         // fixed max in exp2 domain

typedef __bf16 bf16_t;
typedef __attribute__((ext_vector_type(8))) __bf16 bf16x8;
typedef __attribute__((ext_vector_type(4))) __bf16 bf16x4;
typedef __attribute__((ext_vector_type(4))) float f32x4;

__device__ inline bf16_t f2bf(float f) {
    unsigned int x; __builtin_memcpy(&x, &f, 4);
    unsigned int r = (x + 0x7FFFu + ((x >> 16) & 1u)) >> 16;  // RNE
    unsigned short us = (unsigned short)r;
    bf16_t b; __builtin_memcpy(&b, &us, 2); return b;
}
__device__ inline unsigned int fbits(float f) {
    unsigned int x; __builtin_memcpy(&x, &f, 4); return x;
}
__device__ inline unsigned int pack_bf2(float a, float b) {  // round-half-up
    return ((fbits(a) + 0x8000u) >> 16) | ((fbits(b) + 0x8000u) & 0xFFFF0000u);
}
__device__ inline void gload16(const void* g, void* lds_base) {
    __builtin_amdgcn_global_load_lds(
        (const __attribute__((address_space(1))) void*)g,
        (__attribute__((address_space(3))) void*)lds_base, 16, 0, 0);
}

// ---------- prep: dense grid; blocks 0..2047 x-cvt, 2048..2559 pack 4 weights ----------
__global__ __launch_bounds__(256)
void prep_kernel(const float* __restrict__ x, bf16_t* __restrict__ xb,
                 const float* __restrict__ W0, const float* __restrict__ W1,
                 const float* __restrict__ W2, const float* __restrict__ W3,
                 bf16x8* __restrict__ P0, bf16x8* __restrict__ P1,
                 bf16x8* __restrict__ P2, bf16x8* __restrict__ P3) {
    const int bid = blockIdx.x, tid = threadIdx.x;
    if (bid < 2048) {
        const int i = bid * 512 + tid;
        #pragma unroll
        for (int u = 0; u < 2; ++u) {
            const int j = i + u * 256;
            const float4 v = reinterpret_cast<const float4*>(x)[j];
            bf16x4 o;
            o.x = f2bf(v.x); o.y = f2bf(v.y); o.z = f2bf(v.z); o.w = f2bf(v.w);
            reinterpret_cast<bf16x4*>(xb)[j] = o;
        }
    } else {
        const int t = (bid - 2048) * 256 + tid;   // 0..131071
        const int g = t >> 10, n = t & 1023;
        const float* Ws[4] = {W0, W1, W2, W3};
        bf16x8* Pp[4] = {P0, P1, P2, P3};
        #pragma unroll
        for (int m = 0; m < 4; ++m) {
            bf16x8 v;
            #pragma unroll
            for (int j = 0; j < 8; ++j) v[j] = f2bf(Ws[m][(size_t)(g * 8 + j) * DD + n]);
            Pp[m][(size_t)g * DD + n] = v;
        }
    }
}

// ---------- fused QKV GEMM, 128x128 tile, BK=64; z=0 pre-scales Q by SCL; z=2 -> Vt ----------
__global__ __launch_bounds__(256)
void gemm_qkv(const bf16_t* __restrict__ A,
              const bf16x8* __restrict__ Wp0, const bf16x8* __restrict__ Wp1,
              const bf16x8* __restrict__ Wp2,
              const float* __restrict__ b0, const float* __restrict__ b1,
              const float* __restrict__ b2,
              bf16_t* __restrict__ C0, bf16_t* __restrict__ C1,
              bf16_t* __restrict__ Vt) {
    extern __shared__ char smem[];
    bf16x8 (*As)[8]   = reinterpret_cast<bf16x8(*)[8]>(smem);           // 128r x 64k, swz c^(r&7)
    bf16x8 (*Bs)[128] = reinterpret_cast<bf16x8(*)[128]>(smem + 16384); // [kgrp][n]

    const int z = blockIdx.z;
    const bf16x8* Wp = (z == 0) ? Wp0 : (z == 1) ? Wp1 : Wp2;
    const float* bias = (z == 0) ? b0 : (z == 1) ? b1 : b2;

    const int tid = threadIdx.x;
    const int ln = tid & 63, wv = tid >> 6;
    const int quad = ln >> 4, l15 = ln & 15;
    const int wr = wv >> 1, wc = wv & 1;
    const int m0 = blockIdx.y * 128;
    const int n0 = blockIdx.x * 128;

    int arow[4], acl[4], bg[4], bn[4];
    #pragma unroll
    for (int u = 0; u < 4; ++u) {
        const int S = (wv * 4 + u) * 64 + ln;
        arow[u] = S >> 3; acl[u] = (S & 7) ^ (arow[u] & 7);
        bg[u] = S >> 7;   bn[u] = S & 127;
    }

    f32x4 acc[4][4];
    #pragma unroll
    for (int i = 0; i < 4; ++i)
        #pragma unroll
        for (int j = 0; j < 4; ++j) acc[i][j] = (f32x4){0.f, 0.f, 0.f, 0.f};

    for (int k0 = 0; k0 < DD; k0 += 64) {
        __syncthreads();
        const int kg0 = k0 >> 3;
        #pragma unroll
        for (int u = 0; u < 4; ++u) {
            gload16(&A[(size_t)(m0 + arow[u]) * DD + k0 + acl[u] * 8],
                    smem + (size_t)(wv * 4 + u) * 1024);
            gload16(&Wp[(size_t)(kg0 + bg[u]) * DD + n0 + bn[u]],
                    smem + 16384 + (size_t)(wv * 4 + u) * 1024);
        }
        __syncthreads();

        #pragma unroll
        for (int kk = 0; kk < 2; ++kk) {
            bf16x8 fa[4], fb[4];
            #pragma unroll
            for (int mi = 0; mi < 4; ++mi) {
                const int row = wr * 64 + mi * 16 + l15;
                fa[mi] = As[row][(kk * 4 + quad) ^ (row & 7)];
            }
            #pragma unroll
            for (int ni = 0; ni < 4; ++ni)
                fb[ni] = Bs[kk * 4 + quad][wc * 64 + ni * 16 + l15];
            #pragma unroll
            for (int mi = 0; mi < 4; ++mi)
                #pragma unroll
                for (int ni = 0; ni < 4; ++ni)
                    acc[mi][ni] = __builtin_amdgcn_mfma_f32_16x16x32_bf16(
                        fa[mi], fb[ni], acc[mi][ni], 0, 0, 0);
        }
    }

    if (z < 2) {
        bf16_t* C = (z == 0) ? C0 : C1;
        const float osc = (z == 0) ? SCL : 1.0f;   // pre-scale Q for exp2-domain softmax
        #pragma unroll
        for (int ni = 0; ni < 4; ++ni) {
            const int col = n0 + wc * 64 + ni * 16 + l15;
            const float bv = bias[col];
            #pragma unroll
            for (int mi = 0; mi < 4; ++mi)
                #pragma unroll
                for (int r = 0; r < 4; ++r) {
                    const int row = m0 + wr * 64 + mi * 16 + quad * 4 + r;
                    C[(size_t)row * DD + col] = f2bf((acc[mi][ni][r] + bv) * osc);
                }
        }
    } else {
        unsigned short (*T)[136] = reinterpret_cast<unsigned short(*)[136]>(smem);
        __syncthreads();
        #pragma unroll
        for (int ni = 0; ni < 4; ++ni) {
            const int cl = wc * 64 + ni * 16 + l15;
            const float bv = bias[n0 + cl];
            #pragma unroll
            for (int mi = 0; mi < 4; ++mi) {
                const int rl = wr * 64 + mi * 16 + quad * 4;
                uint2 pk;
                pk.x = pack_bf2(acc[mi][ni][0] + bv, acc[mi][ni][1] + bv);
                pk.y = pack_bf2(acc[mi][ni][2] + bv, acc[mi][ni][3] + bv);
                *reinterpret_cast<uint2*>(&T[cl][rl]) = pk;
            }
        }
        __syncthreads();
        const int b = m0 >> 11, s0 = m0 & 2047, h0 = n0 >> 6;
        #pragma unroll
        for (int u = 0; u < 8; ++u) {
            const int c = u * 256 + tid;
            const int s8 = c & 15, nl = c >> 4;
            const bf16x8 v = *reinterpret_cast<const bf16x8*>(&T[nl][s8 * 8]);
            const int bh = b * 16 + h0 + (nl >> 6), d = nl & 63;
            *reinterpret_cast<bf16x8*>(
                &Vt[((size_t)bh * 64 + d) * SS + s0 + s8 * 8]) = v;
        }
    }
}

// ---------- output GEMM: 128x64 tile, BK=64, fp32 out; 512 blocks = 2/CU ----------
__global__ __launch_bounds__(256)
void gemm_out(const bf16_t* __restrict__ A, const bf16x8* __restrict__ Wp,
              const float* __restrict__ bias, float* __restrict__ C) {
    __shared__ bf16x8 As[128][8];   // swz c^(r&7)
    __shared__ bf16x8 Bs[8][64];

    const int tid = threadIdx.x;
    const int ln = tid & 63, wv = tid >> 6;
    const int quad = ln >> 4, l15 = ln & 15;
    const int wr = wv >> 1, wc = wv & 1;
    const int m0 = blockIdx.y * 128;
    const int n0 = blockIdx.x * 64;

    int arow[4], acl[4], bkg[2], bn[2];
    #pragma unroll
    for (int u = 0; u < 4; ++u) {
        const int S = (wv * 4 + u) * 64 + ln;
        arow[u] = S >> 3; acl[u] = (S & 7) ^ (arow[u] & 7);
    }
    #pragma unroll
    for (int u = 0; u < 2; ++u) {
        const int S = (wv * 2 + u) * 64 + ln;
        bkg[u] = S >> 6; bn[u] = S & 63;
    }

    f32x4 acc[4][2];
    #pragma unroll
    for (int i = 0; i < 4; ++i)
        #pragma unroll
        for (int j = 0; j < 2; ++j) acc[i][j] = (f32x4){0.f, 0.f, 0.f, 0.f};

    for (int k0 = 0; k0 < DD; k0 += 64) {
        __syncthreads();
        const int kg0 = k0 >> 3;
        #pragma unroll
        for (int u = 0; u < 4; ++u)
            gload16(&A[(size_t)(m0 + arow[u]) * DD + k0 + acl[u] * 8],
                    (char*)&As[0][0] + (size_t)(wv * 4 + u) * 1024);
        #pragma unroll
        for (int u = 0; u < 2; ++u)
            gload16(&Wp[(size_t)(kg0 + bkg[u]) * DD + n0 + bn[u]],
                    (char*)&Bs[0][0] + (size_t)(wv * 2 + u) * 1024);
        __syncthreads();

        #pragma unroll
        for (int kk = 0; kk < 2; ++kk) {
            bf16x8 fa[4], fb[2];
            #pragma unroll
            for (int mi = 0; mi < 4; ++mi) {
                const int row = wr * 64 + mi * 16 + l15;
                fa[mi] = As[row][(kk * 4 + quad) ^ (row & 7)];
            }
            #pragma unroll
            for (int ni = 0; ni < 2; ++ni)
                fb[ni] = Bs[kk * 4 + quad][wc * 32 + ni * 16 + l15];
            #pragma unroll
            for (int mi = 0; mi < 4; ++mi)
                #pragma unroll
                for (int ni = 0; ni < 2; ++ni)
                    acc[mi][ni] = __builtin_amdgcn_mfma_f32_16x16x32_bf16(
                        fa[mi], fb[ni], acc[mi][ni], 0, 0, 0);
        }
    }

    #pragma unroll
    for (int ni = 0; ni < 2; ++ni) {
        const int col = n0 + wc * 32 + ni * 16 + l15;
        const float bv = bias[col];
        #pragma unroll
        for (int mi = 0; mi < 4; ++mi)
            #pragma unroll
            for (int r = 0; r < 4; ++r) {
                const int row = m0 + wr * 64 + mi * 16 + quad * 4 + r;
                C[(size_t)row * DD + col] = acc[mi][ni][r] + bv;
            }
    }
}

// ---------- MFMA flash attention: barrier-free, direct global->VGPR K/V fragments ----------
// q-tile 128 (4 waves x 32 q). S^T = K Q'^T (Q pre-scaled); P via fixed-max exp2;
// O^T = V^T P^T; l via ones-MFMA (each lane ends with its own q's l; no shuffles).
// Only LDS: per-wave Ps (P C-layout -> B-operand layout), stride 68 kills conflicts.
__global__ __launch_bounds__(256, 2)
void attn_mfma(const bf16_t* __restrict__ Q, const bf16_t* __restrict__ Kg,
               const bf16_t* __restrict__ Vt, bf16_t* __restrict__ Ctx) {
    __shared__ unsigned short Ps[4][2][16][68];   // 17408 B

    const int tid = threadIdx.x;
    const int ln = tid & 63, w = tid >> 6;
    const int quad = ln >> 4, l15 = ln & 15;
    const int bh = blockIdx.x;
    // complementary swizzle: co-resident blocks get qt pairs summing to 15
    const int tswz = (blockIdx.x + blockIdx.y) & 7;
    const int qt = (blockIdx.y < 8) ? tswz : 15 - tswz;
    const int b = bh >> 4, h = bh & 15;
    const size_t rowbase = (size_t)b * SS;
    const int col0 = h * 64;

    bf16x8 fq[2][2];
    #pragma unroll
    for (int rg = 0; rg < 2; ++rg) {
        const int qrow = qt * 128 + w * 32 + rg * 16 + l15;
        #pragma unroll
        for (int kk = 0; kk < 2; ++kk)
            fq[rg][kk] = *reinterpret_cast<const bf16x8*>(
                &Q[(rowbase + qrow) * DD + col0 + kk * 32 + quad * 8]);
    }

    bf16x8 vone;
    #pragma unroll
    for (int i = 0; i < 8; ++i) vone[i] = (bf16_t)1.0f;

    f32x4 acc_o[2][4];
    #pragma unroll
    for (int rg = 0; rg < 2; ++rg)
        #pragma unroll
        for (int i = 0; i < 4; ++i) acc_o[rg][i] = (f32x4){0.f, 0.f, 0.f, 0.f};
    f32x4 acc_l[2] = {(f32x4){0.f, 0.f, 0.f, 0.f}, (f32x4){0.f, 0.f, 0.f, 0.f}};

    const int swz = l15 & 7;

    // dq >= 112 -> fully unmasked; dq < 0 -> q-group fully masked (skip)
    auto compute_tile = [&](int kt, int dq0, int dq1) {
        // K fragments direct from global (A-layout: m=key%16=l15, k=kk*32+quad*8+j)
        bf16x8 fk[4][2];
        #pragma unroll
        for (int ni = 0; ni < 4; ++ni) {
            const size_t kr = (rowbase + kt * 64 + ni * 16 + l15) * DD + col0;
            #pragma unroll
            for (int kk = 0; kk < 2; ++kk)
                fk[ni][kk] = *reinterpret_cast<const bf16x8*>(&Kg[kr + kk * 32 + quad * 8]);
        }
        // V^T fragments direct from global (A-layout: m=d%16=l15, k=key)
        bf16x8 fv[4][2];
        #pragma unroll
        for (int nd = 0; nd < 4; ++nd) {
            const size_t vr = ((size_t)bh * 64 + nd * 16 + l15) * SS + kt * 64;
            #pragma unroll
            for (int kk = 0; kk < 2; ++kk)
                fv[nd][kk] = *reinterpret_cast<const bf16x8*>(&Vt[vr + kk * 32 + quad * 8]);
        }

        const int dq[2] = {dq0, dq1};
        #pragma unroll
        for (int rg = 0; rg < 2; ++rg) {
            if (dq[rg] < 0) continue;
            unsigned short* const psw = &Ps[w][rg][l15][0];
            #pragma unroll
            for (int ni = 0; ni < 4; ++ni) {
                const int slot = ni * 4 + quad;
                unsigned short* pdst = psw + (((slot >> 1) ^ swz) * 8 + (slot & 1) * 4);
                const int g = ni * 16;
                if (g > dq[rg]) {
                    *reinterpret_cast<uint2*>(pdst) = (uint2){0u, 0u};
                    continue;
                }
                f32x4 st = (f32x4){0.f, 0.f, 0.f, 0.f};
                st = __builtin_amdgcn_mfma_f32_16x16x32_bf16(fk[ni][0], fq[rg][0], st, 0, 0, 0);
                st = __builtin_amdgcn_mfma_f32_16x16x32_bf16(fk[ni][1], fq[rg][1], st, 0, 0, 0);
                float p[4];
                #pragma unroll
                for (int r = 0; r < 4; ++r) {
                    p[r] = __builtin_amdgcn_exp2f(st[r] - FM);
                    if (g == dq[rg] && (quad * 4 + r) > l15) p[r] = 0.f;
                }
                uint2 pk;
                pk.x = pack_bf2(p[0], p[1]);
                pk.y = pack_bf2(p[2], p[3]);
                *reinterpret_cast<uint2*>(pdst) = pk;
            }
        }

        // O^T += V^T P^T ; l += ones * P^T (lane's col q=l15 -> direct l)
        #pragma unroll
        for (int kk = 0; kk < 2; ++kk) {
            bf16x8 fp[2];
            #pragma unroll
            for (int rg = 0; rg < 2; ++rg)
                if (dq[rg] >= 0)
                    fp[rg] = *reinterpret_cast<const bf16x8*>(
                        &Ps[w][rg][l15][((kk * 4 + quad) ^ swz) * 8]);
            if (dq0 >= 0)
                acc_l[0] = __builtin_amdgcn_mfma_f32_16x16x32_bf16(vone, fp[0], acc_l[0], 0, 0, 0);
            if (dq1 >= 0)
                acc_l[1] = __builtin_amdgcn_mfma_f32_16x16x32_bf16(vone, fp[1], acc_l[1], 0, 0, 0);
            #pragma unroll
            for (int nd = 0; nd < 4; ++nd) {
                if (dq0 >= 0)
                    acc_o[0][nd] = __builtin_amdgcn_mfma_f32_16x16x32_bf16(
                        fv[nd][kk], fp[0], acc_o[0][nd], 0, 0, 0);
                if (dq1 >= 0)
                    acc_o[1][nd] = __builtin_amdgcn_mfma_f32_16x16x32_bf16(
                        fv[nd][kk], fp[1], acc_o[1][nd], 0, 0, 0);
            }
        }
    };

    const int nfull = 2 * qt;                  // fully-unmasked tiles
    for (int kt = 0; kt < nfull; ++kt) compute_tile(kt, 112, 112);
    compute_tile(nfull,     w * 32,      w * 32 + 16);        // diagonal tiles
    compute_tile(nfull + 1, w * 32 - 64, w * 32 - 48);

    #pragma unroll
    for (int rg = 0; rg < 2; ++rg) {
        const float inv = 1.f / acc_l[rg][0];
        const size_t orow = (rowbase + qt * 128 + w * 32 + rg * 16 + l15) * DD + col0;
        #pragma unroll
        for (int nd = 0; nd < 4; ++nd) {
            uint2 ov;
            ov.x = pack_bf2(acc_o[rg][nd][0] * inv, acc_o[rg][nd][1] * inv);
            ov.y = pack_bf2(acc_o[rg][nd][2] * inv, acc_o[rg][nd][3] * inv);
            *reinterpret_cast<uint2*>(&Ctx[orow + nd * 16 + quad * 4]) = ov;
        }
    }
}

extern "C" void kernel_launch(void* const* d_in, const int* in_sizes, int n_in,
                              void* d_out, int out_size, void* d_ws, size_t ws_size,
                              hipStream_t stream) {
    const float* x  = (const float*)d_in[0];
    const float* Wq = (const float*)d_in[1];
    const float* bq = (const float*)d_in[2];
    const float* Wk = (const float*)d_in[3];
    const float* bk = (const float*)d_in[4];
    const float* Wv = (const float*)d_in[5];
    const float* bv = (const float*)d_in[6];
    const float* Wo = (const float*)d_in[7];
    const float* bo = (const float*)d_in[8];
    float* out = (float*)d_out;

    const size_t M = (size_t)BB * SS;        // 4096
    const size_t mat = M * DD;               // 4M elements
    const size_t wsz = (size_t)DD * DD;

    bf16_t* ws = (bf16_t*)d_ws;
    bf16_t* xb   = ws;                       // 4M
    bf16_t* Wqp  = ws + mat;                 // 1M each
    bf16_t* Wkp  = Wqp + wsz;
    bf16_t* Wvp  = Wkp + wsz;
    bf16_t* Wop  = Wvp + wsz;
    bf16_t* Qb   = Wop + wsz;                // 4M
    bf16_t* Kb   = Qb + mat;                 // 4M
    bf16_t* Vtb  = Kb + mat;                 // 4M
    bf16_t* Ctxb = Vtb + mat;                // 4M -> 48 MB total

    dim3 blk(256);
    hipLaunchKernelGGL(prep_kernel, dim3(2560), blk, 0, stream,
                       x, xb, Wq, Wk, Wv, Wo,
                       (bf16x8*)Wqp, (bf16x8*)Wkp, (bf16x8*)Wvp, (bf16x8*)Wop);

    hipLaunchKernelGGL(gemm_qkv, dim3(DD / 128, M / 128, 3), blk, 34816, stream,
                       xb, (const bf16x8*)Wqp, (const bf16x8*)Wkp, (const bf16x8*)Wvp,
                       bq, bk, bv, Qb, Kb, Vtb);

    hipLaunchKernelGGL(attn_mfma, dim3(BB * HH, SS / 128), blk, 0, stream,
                       Qb, Kb, Vtb, Ctxb);

    hipLaunchKernelGGL(gemm_out, dim3(DD / 64, M / 128), blk, 0, stream,
                       Ctxb, (const bf16x8*)Wop, bo, out);
}

// Round 10
// 217.028 us; speedup vs baseline: 1.0437x; 1.0437x over previous
//
#include <hip/hip_runtime.h>
#include <math.h>

#define BB 2
#define SS 2048
#define DD 1024
#define HH 16
#define HDIM 64

#define SCL 0.18033688f   // (1/sqrt(64)) * log2(e), folded into Q at QKV epilogue
#define FM  12.0f         // fixed max in exp2 domain

typedef __bf16 bf16_t;
typedef __attribute__((ext_vector_type(8))) __bf16 bf16x8;
typedef __attribute__((ext_vector_type(4))) __bf16 bf16x4;
typedef __attribute__((ext_vector_type(4))) float f32x4;

template<int N> struct IC { static constexpr int v = N; };

__device__ inline bf16_t f2bf(float f) {
    unsigned int x; __builtin_memcpy(&x, &f, 4);
    unsigned int r = (x + 0x7FFFu + ((x >> 16) & 1u)) >> 16;  // RNE
    unsigned short us = (unsigned short)r;
    bf16_t b; __builtin_memcpy(&b, &us, 2); return b;
}
__device__ inline unsigned int fbits(float f) {
    unsigned int x; __builtin_memcpy(&x, &f, 4); return x;
}
__device__ inline unsigned int pack_bf2(float a, float b) {  // round-half-up
    return ((fbits(a) + 0x8000u) >> 16) | ((fbits(b) + 0x8000u) & 0xFFFF0000u);
}
__device__ inline void gload16(const void* g, void* lds_base) {
    __builtin_amdgcn_global_load_lds(
        (const __attribute__((address_space(1))) void*)g,
        (__attribute__((address_space(3))) void*)lds_base, 16, 0, 0);
}

// ---------- prep: dense grid; blocks 0..2047 x-cvt, 2048..2559 pack 4 weights ----------
__global__ __launch_bounds__(256)
void prep_kernel(const float* __restrict__ x, bf16_t* __restrict__ xb,
                 const float* __restrict__ W0, const float* __restrict__ W1,
                 const float* __restrict__ W2, const float* __restrict__ W3,
                 bf16x8* __restrict__ P0, bf16x8* __restrict__ P1,
                 bf16x8* __restrict__ P2, bf16x8* __restrict__ P3) {
    const int bid = blockIdx.x, tid = threadIdx.x;
    if (bid < 2048) {
        const int i = bid * 512 + tid;
        #pragma unroll
        for (int u = 0; u < 2; ++u) {
            const int j = i + u * 256;
            const float4 v = reinterpret_cast<const float4*>(x)[j];
            bf16x4 o;
            o.x = f2bf(v.x); o.y = f2bf(v.y); o.z = f2bf(v.z); o.w = f2bf(v.w);
            reinterpret_cast<bf16x4*>(xb)[j] = o;
        }
    } else {
        const int t = (bid - 2048) * 256 + tid;   // 0..131071
        const int g = t >> 10, n = t & 1023;
        const float* Ws[4] = {W0, W1, W2, W3};
        bf16x8* Pp[4] = {P0, P1, P2, P3};
        #pragma unroll
        for (int m = 0; m < 4; ++m) {
            bf16x8 v;
            #pragma unroll
            for (int j = 0; j < 8; ++j) v[j] = f2bf(Ws[m][(size_t)(g * 8 + j) * DD + n]);
            Pp[m][(size_t)g * DD + n] = v;
        }
    }
}

// ---------- fused QKV GEMM, 128x128 tile, BK=64; z=0 pre-scales Q by SCL; z=2 -> Vt ----------
__global__ __launch_bounds__(256)
void gemm_qkv(const bf16_t* __restrict__ A,
              const bf16x8* __restrict__ Wp0, const bf16x8* __restrict__ Wp1,
              const bf16x8* __restrict__ Wp2,
              const float* __restrict__ b0, const float* __restrict__ b1,
              const float* __restrict__ b2,
              bf16_t* __restrict__ C0, bf16_t* __restrict__ C1,
              bf16_t* __restrict__ Vt) {
    extern __shared__ char smem[];
    bf16x8 (*As)[8]   = reinterpret_cast<bf16x8(*)[8]>(smem);           // 128r x 64k, swz c^(r&7)
    bf16x8 (*Bs)[128] = reinterpret_cast<bf16x8(*)[128]>(smem + 16384); // [kgrp][n]

    const int z = blockIdx.z;
    const bf16x8* Wp = (z == 0) ? Wp0 : (z == 1) ? Wp1 : Wp2;
    const float* bias = (z == 0) ? b0 : (z == 1) ? b1 : b2;

    const int tid = threadIdx.x;
    const int ln = tid & 63, wv = tid >> 6;
    const int quad = ln >> 4, l15 = ln & 15;
    const int wr = wv >> 1, wc = wv & 1;
    const int m0 = blockIdx.y * 128;
    const int n0 = blockIdx.x * 128;

    int arow[4], acl[4], bg[4], bn[4];
    #pragma unroll
    for (int u = 0; u < 4; ++u) {
        const int S = (wv * 4 + u) * 64 + ln;
        arow[u] = S >> 3; acl[u] = (S & 7) ^ (arow[u] & 7);
        bg[u] = S >> 7;   bn[u] = S & 127;
    }

    f32x4 acc[4][4];
    #pragma unroll
    for (int i = 0; i < 4; ++i)
        #pragma unroll
        for (int j = 0; j < 4; ++j) acc[i][j] = (f32x4){0.f, 0.f, 0.f, 0.f};

    for (int k0 = 0; k0 < DD; k0 += 64) {
        __syncthreads();
        const int kg0 = k0 >> 3;
        #pragma unroll
        for (int u = 0; u < 4; ++u) {
            gload16(&A[(size_t)(m0 + arow[u]) * DD + k0 + acl[u] * 8],
                    smem + (size_t)(wv * 4 + u) * 1024);
            gload16(&Wp[(size_t)(kg0 + bg[u]) * DD + n0 + bn[u]],
                    smem + 16384 + (size_t)(wv * 4 + u) * 1024);
        }
        __syncthreads();

        #pragma unroll
        for (int kk = 0; kk < 2; ++kk) {
            bf16x8 fa[4], fb[4];
            #pragma unroll
            for (int mi = 0; mi < 4; ++mi) {
                const int row = wr * 64 + mi * 16 + l15;
                fa[mi] = As[row][(kk * 4 + quad) ^ (row & 7)];
            }
            #pragma unroll
            for (int ni = 0; ni < 4; ++ni)
                fb[ni] = Bs[kk * 4 + quad][wc * 64 + ni * 16 + l15];
            #pragma unroll
            for (int mi = 0; mi < 4; ++mi)
                #pragma unroll
                for (int ni = 0; ni < 4; ++ni)
                    acc[mi][ni] = __builtin_amdgcn_mfma_f32_16x16x32_bf16(
                        fa[mi], fb[ni], acc[mi][ni], 0, 0, 0);
        }
    }

    if (z < 2) {
        bf16_t* C = (z == 0) ? C0 : C1;
        const float osc = (z == 0) ? SCL : 1.0f;   // pre-scale Q for exp2-domain softmax
        #pragma unroll
        for (int ni = 0; ni < 4; ++ni) {
            const int col = n0 + wc * 64 + ni * 16 + l15;
            const float bv = bias[col];
            #pragma unroll
            for (int mi = 0; mi < 4; ++mi)
                #pragma unroll
                for (int r = 0; r < 4; ++r) {
                    const int row = m0 + wr * 64 + mi * 16 + quad * 4 + r;
                    C[(size_t)row * DD + col] = f2bf((acc[mi][ni][r] + bv) * osc);
                }
        }
    } else {
        unsigned short (*T)[136] = reinterpret_cast<unsigned short(*)[136]>(smem);
        __syncthreads();
        #pragma unroll
        for (int ni = 0; ni < 4; ++ni) {
            const int cl = wc * 64 + ni * 16 + l15;
            const float bv = bias[n0 + cl];
            #pragma unroll
            for (int mi = 0; mi < 4; ++mi) {
                const int rl = wr * 64 + mi * 16 + quad * 4;
                uint2 pk;
                pk.x = pack_bf2(acc[mi][ni][0] + bv, acc[mi][ni][1] + bv);
                pk.y = pack_bf2(acc[mi][ni][2] + bv, acc[mi][ni][3] + bv);
                *reinterpret_cast<uint2*>(&T[cl][rl]) = pk;
            }
        }
        __syncthreads();
        const int b = m0 >> 11, s0 = m0 & 2047, h0 = n0 >> 6;
        #pragma unroll
        for (int u = 0; u < 8; ++u) {
            const int c = u * 256 + tid;
            const int s8 = c & 15, nl = c >> 4;
            const bf16x8 v = *reinterpret_cast<const bf16x8*>(&T[nl][s8 * 8]);
            const int bh = b * 16 + h0 + (nl >> 6), d = nl & 63;
            *reinterpret_cast<bf16x8*>(
                &Vt[((size_t)bh * 64 + d) * SS + s0 + s8 * 8]) = v;
        }
    }
}

// ---------- output GEMM: 128x64 tile, BK=64, fp32 out; 512 blocks = 2/CU ----------
__global__ __launch_bounds__(256)
void gemm_out(const bf16_t* __restrict__ A, const bf16x8* __restrict__ Wp,
              const float* __restrict__ bias, float* __restrict__ C) {
    __shared__ bf16x8 As[128][8];   // swz c^(r&7)
    __shared__ bf16x8 Bs[8][64];

    const int tid = threadIdx.x;
    const int ln = tid & 63, wv = tid >> 6;
    const int quad = ln >> 4, l15 = ln & 15;
    const int wr = wv >> 1, wc = wv & 1;
    const int m0 = blockIdx.y * 128;
    const int n0 = blockIdx.x * 64;

    int arow[4], acl[4], bkg[2], bn[2];
    #pragma unroll
    for (int u = 0; u < 4; ++u) {
        const int S = (wv * 4 + u) * 64 + ln;
        arow[u] = S >> 3; acl[u] = (S & 7) ^ (arow[u] & 7);
    }
    #pragma unroll
    for (int u = 0; u < 2; ++u) {
        const int S = (wv * 2 + u) * 64 + ln;
        bkg[u] = S >> 6; bn[u] = S & 63;
    }

    f32x4 acc[4][2];
    #pragma unroll
    for (int i = 0; i < 4; ++i)
        #pragma unroll
        for (int j = 0; j < 2; ++j) acc[i][j] = (f32x4){0.f, 0.f, 0.f, 0.f};

    for (int k0 = 0; k0 < DD; k0 += 64) {
        __syncthreads();
        const int kg0 = k0 >> 3;
        #pragma unroll
        for (int u = 0; u < 4; ++u)
            gload16(&A[(size_t)(m0 + arow[u]) * DD + k0 + acl[u] * 8],
                    (char*)&As[0][0] + (size_t)(wv * 4 + u) * 1024);
        #pragma unroll
        for (int u = 0; u < 2; ++u)
            gload16(&Wp[(size_t)(kg0 + bkg[u]) * DD + n0 + bn[u]],
                    (char*)&Bs[0][0] + (size_t)(wv * 2 + u) * 1024);
        __syncthreads();

        #pragma unroll
        for (int kk = 0; kk < 2; ++kk) {
            bf16x8 fa[4], fb[2];
            #pragma unroll
            for (int mi = 0; mi < 4; ++mi) {
                const int row = wr * 64 + mi * 16 + l15;
                fa[mi] = As[row][(kk * 4 + quad) ^ (row & 7)];
            }
            #pragma unroll
            for (int ni = 0; ni < 2; ++ni)
                fb[ni] = Bs[kk * 4 + quad][wc * 32 + ni * 16 + l15];
            #pragma unroll
            for (int mi = 0; mi < 4; ++mi)
                #pragma unroll
                for (int ni = 0; ni < 2; ++ni)
                    acc[mi][ni] = __builtin_amdgcn_mfma_f32_16x16x32_bf16(
                        fa[mi], fb[ni], acc[mi][ni], 0, 0, 0);
        }
    }

    #pragma unroll
    for (int ni = 0; ni < 2; ++ni) {
        const int col = n0 + wc * 32 + ni * 16 + l15;
        const float bv = bias[col];
        #pragma unroll
        for (int mi = 0; mi < 4; ++mi)
            #pragma unroll
            for (int r = 0; r < 4; ++r) {
                const int row = m0 + wr * 64 + mi * 16 + quad * 4 + r;
                C[(size_t)row * DD + col] = acc[mi][ni][r] + bv;
            }
    }
}

// ---------- MFMA flash attention: barrier-free + register double-buffered K/V ----------
// Ping-pong fragment buffers: tile k+1's 16 global loads issue BEFORE tile k's
// compute, so vmcnt waits land ~500 cycles after issue (AITER-style overlap,
// no __syncthreads anywhere). S^T = K Q'^T; fixed-max exp2; O^T = V^T P^T;
// l via ones-MFMA. Per-wave Ps in LDS (stride 68 = conflict-free).
__global__ __launch_bounds__(256, 2)
void attn_mfma(const bf16_t* __restrict__ Q, const bf16_t* __restrict__ Kg,
               const bf16_t* __restrict__ Vt, bf16_t* __restrict__ Ctx) {
    __shared__ unsigned short Ps[4][2][16][68];   // 17408 B

    const int tid = threadIdx.x;
    const int ln = tid & 63, w = tid >> 6;
    const int quad = ln >> 4, l15 = ln & 15;
    const int bh = blockIdx.x;
    // complementary swizzle: co-resident blocks get qt pairs summing to 15
    const int tswz = (blockIdx.x + blockIdx.y) & 7;
    const int qt = (blockIdx.y < 8) ? tswz : 15 - tswz;
    const int b = bh >> 4, h = bh & 15;
    const size_t rowbase = (size_t)b * SS;
    const int col0 = h * 64;

    bf16x8 fq[2][2];
    #pragma unroll
    for (int rg = 0; rg < 2; ++rg) {
        const int qrow = qt * 128 + w * 32 + rg * 16 + l15;
        #pragma unroll
        for (int kk = 0; kk < 2; ++kk)
            fq[rg][kk] = *reinterpret_cast<const bf16x8*>(
                &Q[(rowbase + qrow) * DD + col0 + kk * 32 + quad * 8]);
    }

    bf16x8 vone;
    #pragma unroll
    for (int i = 0; i < 8; ++i) vone[i] = (bf16_t)1.0f;

    f32x4 acc_o[2][4];
    #pragma unroll
    for (int rg = 0; rg < 2; ++rg)
        #pragma unroll
        for (int i = 0; i < 4; ++i) acc_o[rg][i] = (f32x4){0.f, 0.f, 0.f, 0.f};
    f32x4 acc_l[2] = {(f32x4){0.f, 0.f, 0.f, 0.f}, (f32x4){0.f, 0.f, 0.f, 0.f}};

    const int swz = l15 & 7;

    bf16x8 fk[2][4][2], fv[2][4][2];   // ping-pong K / V^T fragment buffers

    auto load_tile = [&](auto B, int kt) {
        constexpr int bf = decltype(B)::v;
        #pragma unroll
        for (int ni = 0; ni < 4; ++ni) {
            const bf16_t* kr = &Kg[(rowbase + kt * 64 + ni * 16 + l15) * DD + col0 + quad * 8];
            fk[bf][ni][0] = *reinterpret_cast<const bf16x8*>(kr);
            fk[bf][ni][1] = *reinterpret_cast<const bf16x8*>(kr + 32);
            const bf16_t* vr = &Vt[((size_t)bh * 64 + ni * 16 + l15) * SS + kt * 64 + quad * 8];
            fv[bf][ni][0] = *reinterpret_cast<const bf16x8*>(vr);
            fv[bf][ni][1] = *reinterpret_cast<const bf16x8*>(vr + 32);
        }
    };

    // dq >= 112 -> fully unmasked; dq < 0 -> q-group fully masked (skip)
    auto compute_tile = [&](auto B, int dq0, int dq1) {
        constexpr int bf = decltype(B)::v;
        const int dq[2] = {dq0, dq1};
        #pragma unroll
        for (int rg = 0; rg < 2; ++rg) {
            if (dq[rg] < 0) continue;
            unsigned short* const psw = &Ps[w][rg][l15][0];
            #pragma unroll
            for (int ni = 0; ni < 4; ++ni) {
                const int slot = ni * 4 + quad;
                unsigned short* pdst = psw + (((slot >> 1) ^ swz) * 8 + (slot & 1) * 4);
                const int g = ni * 16;
                if (g > dq[rg]) {
                    *reinterpret_cast<uint2*>(pdst) = (uint2){0u, 0u};
                    continue;
                }
                f32x4 st = (f32x4){0.f, 0.f, 0.f, 0.f};
                st = __builtin_amdgcn_mfma_f32_16x16x32_bf16(fk[bf][ni][0], fq[rg][0], st, 0, 0, 0);
                st = __builtin_amdgcn_mfma_f32_16x16x32_bf16(fk[bf][ni][1], fq[rg][1], st, 0, 0, 0);
                float p[4];
                #pragma unroll
                for (int r = 0; r < 4; ++r) {
                    p[r] = __builtin_amdgcn_exp2f(st[r] - FM);
                    if (g == dq[rg] && (quad * 4 + r) > l15) p[r] = 0.f;
                }
                uint2 pk;
                pk.x = pack_bf2(p[0], p[1]);
                pk.y = pack_bf2(p[2], p[3]);
                *reinterpret_cast<uint2*>(pdst) = pk;
            }
        }

        // O^T += V^T P^T ; l += ones * P^T (lane's col q=l15 -> direct l)
        #pragma unroll
        for (int kk = 0; kk < 2; ++kk) {
            bf16x8 fp[2];
            #pragma unroll
            for (int rg = 0; rg < 2; ++rg)
                if (dq[rg] >= 0)
                    fp[rg] = *reinterpret_cast<const bf16x8*>(
                        &Ps[w][rg][l15][((kk * 4 + quad) ^ swz) * 8]);
            if (dq0 >= 0)
                acc_l[0] = __builtin_amdgcn_mfma_f32_16x16x32_bf16(vone, fp[0], acc_l[0], 0, 0, 0);
            if (dq1 >= 0)
                acc_l[1] = __builtin_amdgcn_mfma_f32_16x16x32_bf16(vone, fp[1], acc_l[1], 0, 0, 0);
            #pragma unroll
            for (int nd = 0; nd < 4; ++nd) {
                if (dq0 >= 0)
                    acc_o[0][nd] = __builtin_amdgcn_mfma_f32_16x16x32_bf16(
                        fv[bf][nd][kk], fp[0], acc_o[0][nd], 0, 0, 0);
                if (dq1 >= 0)
                    acc_o[1][nd] = __builtin_amdgcn_mfma_f32_16x16x32_bf16(
                        fv[bf][nd][kk], fp[1], acc_o[1][nd], 0, 0, 0);
            }
        }
    };

    const int nfull = 2 * qt;           // fully-unmasked tiles
    const int ntiles = nfull + 2;       // + 2 diagonal tiles (always even)
    auto dqa = [&](int kt) { return (kt < nfull) ? 112 : w * 32 - (kt - nfull) * 64; };
    auto dqb = [&](int kt) { return (kt < nfull) ? 112 : w * 32 + 16 - (kt - nfull) * 64; };

    load_tile(IC<0>{}, 0);
    for (int kt = 0; kt < ntiles; kt += 2) {
        load_tile(IC<1>{}, kt + 1);                 // prefetch before consuming buf0
        compute_tile(IC<0>{}, dqa(kt), dqb(kt));
        if (kt + 2 < ntiles) load_tile(IC<0>{}, kt + 2);
        compute_tile(IC<1>{}, dqa(kt + 1), dqb(kt + 1));
    }

    #pragma unroll
    for (int rg = 0; rg < 2; ++rg) {
        const float inv = 1.f / acc_l[rg][0];
        const size_t orow = (rowbase + qt * 128 + w * 32 + rg * 16 + l15) * DD + col0;
        #pragma unroll
        for (int nd = 0; nd < 4; ++nd) {
            uint2 ov;
            ov.x = pack_bf2(acc_o[rg][nd][0] * inv, acc_o[rg][nd][1] * inv);
            ov.y = pack_bf2(acc_o[rg][nd][2] * inv, acc_o[rg][nd][3] * inv);
            *reinterpret_cast<uint2*>(&Ctx[orow + nd * 16 + quad * 4]) = ov;
        }
    }
}

extern "C" void kernel_launch(void* const* d_in, const int* in_sizes, int n_in,
                              void* d_out, int out_size, void* d_ws, size_t ws_size,
                              hipStream_t stream) {
    const float* x  = (const float*)d_in[0];
    const float* Wq = (const float*)d_in[1];
    const float* bq = (const float*)d_in[2];
    const float* Wk = (const float*)d_in[3];
    const float* bk = (const float*)d_in[4];
    const float* Wv = (const float*)d_in[5];
    const float* bv = (const float*)d_in[6];
    const float* Wo = (const float*)d_in[7];
    const float* bo = (const float*)d_in[8];
    float* out = (float*)d_out;

    const size_t M = (size_t)BB * SS;        // 4096
    const size_t mat = M * DD;               // 4M elements
    const size_t wsz = (size_t)DD * DD;

    bf16_t* ws = (bf16_t*)d_ws;
    bf16_t* xb   = ws;                       // 4M
    bf16_t* Wqp  = ws + mat;                 // 1M each
    bf16_t* Wkp  = Wqp + wsz;
    bf16_t* Wvp  = Wkp + wsz;
    bf16_t* Wop  = Wvp + wsz;
    bf16_t* Qb   = Wop + wsz;                // 4M
    bf16_t* Kb   = Qb + mat;                 // 4M
    bf16_t* Vtb  = Kb + mat;                 // 4M
    bf16_t* Ctxb = Vtb + mat;                // 4M -> 48 MB total

    dim3 blk(256);
    hipLaunchKernelGGL(prep_kernel, dim3(2560), blk, 0, stream,
                       x, xb, Wq, Wk, Wv, Wo,
                       (bf16x8*)Wqp, (bf16x8*)Wkp, (bf16x8*)Wvp, (bf16x8*)Wop);

    hipLaunchKernelGGL(gemm_qkv, dim3(DD / 128, M / 128, 3), blk, 34816, stream,
                       xb, (const bf16x8*)Wqp, (const bf16x8*)Wkp, (const bf16x8*)Wvp,
                       bq, bk, bv, Qb, Kb, Vtb);

    hipLaunchKernelGGL(attn_mfma, dim3(BB * HH, SS / 128), blk, 0, stream,
                       Qb, Kb, Vtb, Ctxb);

    hipLaunchKernelGGL(gemm_out, dim3(DD / 64, M / 128), blk, 0, stream,
                       Ctxb, (const bf16x8*)Wop, bo, out);
}

// Round 11
// 207.369 us; speedup vs baseline: 1.0923x; 1.0466x over previous
//
#include <hip/hip_runtime.h>
#include <math.h>

#define BB 2
#define SS 2048
#define DD 1024
#define HH 16
#define HDIM 64

#define SCL 0.18033688f   // (1/sqrt(64)) * log2(e), folded into Q at QKV epilogue
#define FM  12.0f         // fixed max in exp2 domain

typedef __bf16 bf16_t;
typedef __attribute__((ext_vector_type(8))) __bf16 bf16x8;
typedef __attribute__((ext_vector_type(4))) __bf16 bf16x4;
typedef __attribute__((ext_vector_type(4))) float f32x4;

__device__ inline bf16_t f2bf(float f) {
    unsigned int x; __builtin_memcpy(&x, &f, 4);
    unsigned int r = (x + 0x7FFFu + ((x >> 16) & 1u)) >> 16;  // RNE
    unsigned short us = (unsigned short)r;
    bf16_t b; __builtin_memcpy(&b, &us, 2); return b;
}
__device__ inline unsigned int fbits(float f) {
    unsigned int x; __builtin_memcpy(&x, &f, 4); return x;
}
__device__ inline unsigned int pack_bf2(float a, float b) {  // round-half-up
    return ((fbits(a) + 0x8000u) >> 16) | ((fbits(b) + 0x8000u) & 0xFFFF0000u);
}
__device__ inline void gload16(const void* g, void* lds_base) {
    __builtin_amdgcn_global_load_lds(
        (const __attribute__((address_space(1))) void*)g,
        (__attribute__((address_space(3))) void*)lds_base, 16, 0, 0);
}

// ---------- prep: dense grid; blocks 0..2047 x-cvt, 2048..2559 pack 4 weights ----------
__global__ __launch_bounds__(256)
void prep_kernel(const float* __restrict__ x, bf16_t* __restrict__ xb,
                 const float* __restrict__ W0, const float* __restrict__ W1,
                 const float* __restrict__ W2, const float* __restrict__ W3,
                 bf16x8* __restrict__ P0, bf16x8* __restrict__ P1,
                 bf16x8* __restrict__ P2, bf16x8* __restrict__ P3) {
    const int bid = blockIdx.x, tid = threadIdx.x;
    if (bid < 2048) {
        const int i = bid * 512 + tid;
        #pragma unroll
        for (int u = 0; u < 2; ++u) {
            const int j = i + u * 256;
            const float4 v = reinterpret_cast<const float4*>(x)[j];
            bf16x4 o;
            o.x = f2bf(v.x); o.y = f2bf(v.y); o.z = f2bf(v.z); o.w = f2bf(v.w);
            reinterpret_cast<bf16x4*>(xb)[j] = o;
        }
    } else {
        const int t = (bid - 2048) * 256 + tid;   // 0..131071
        const int g = t >> 10, n = t & 1023;
        const float* Ws[4] = {W0, W1, W2, W3};
        bf16x8* Pp[4] = {P0, P1, P2, P3};
        #pragma unroll
        for (int m = 0; m < 4; ++m) {
            bf16x8 v;
            #pragma unroll
            for (int j = 0; j < 8; ++j) v[j] = f2bf(Ws[m][(size_t)(g * 8 + j) * DD + n]);
            Pp[m][(size_t)g * DD + n] = v;
        }
    }
}

// ---------- fused QKV GEMM, 128x128 tile, BK=64; z=0 pre-scales Q by SCL; z=2 -> Vt ----------
__global__ __launch_bounds__(256)
void gemm_qkv(const bf16_t* __restrict__ A,
              const bf16x8* __restrict__ Wp0, const bf16x8* __restrict__ Wp1,
              const bf16x8* __restrict__ Wp2,
              const float* __restrict__ b0, const float* __restrict__ b1,
              const float* __restrict__ b2,
              bf16_t* __restrict__ C0, bf16_t* __restrict__ C1,
              bf16_t* __restrict__ Vt) {
    extern __shared__ char smem[];
    bf16x8 (*As)[8]   = reinterpret_cast<bf16x8(*)[8]>(smem);           // 128r x 64k, swz c^(r&7)
    bf16x8 (*Bs)[128] = reinterpret_cast<bf16x8(*)[128]>(smem + 16384); // [kgrp][n]

    const int z = blockIdx.z;
    const bf16x8* Wp = (z == 0) ? Wp0 : (z == 1) ? Wp1 : Wp2;
    const float* bias = (z == 0) ? b0 : (z == 1) ? b1 : b2;

    const int tid = threadIdx.x;
    const int ln = tid & 63, wv = tid >> 6;
    const int quad = ln >> 4, l15 = ln & 15;
    const int wr = wv >> 1, wc = wv & 1;
    const int m0 = blockIdx.y * 128;
    const int n0 = blockIdx.x * 128;

    int arow[4], acl[4], bg[4], bn[4];
    #pragma unroll
    for (int u = 0; u < 4; ++u) {
        const int S = (wv * 4 + u) * 64 + ln;
        arow[u] = S >> 3; acl[u] = (S & 7) ^ (arow[u] & 7);
        bg[u] = S >> 7;   bn[u] = S & 127;
    }

    f32x4 acc[4][4];
    #pragma unroll
    for (int i = 0; i < 4; ++i)
        #pragma unroll
        for (int j = 0; j < 4; ++j) acc[i][j] = (f32x4){0.f, 0.f, 0.f, 0.f};

    for (int k0 = 0; k0 < DD; k0 += 64) {
        __syncthreads();
        const int kg0 = k0 >> 3;
        #pragma unroll
        for (int u = 0; u < 4; ++u) {
            gload16(&A[(size_t)(m0 + arow[u]) * DD + k0 + acl[u] * 8],
                    smem + (size_t)(wv * 4 + u) * 1024);
            gload16(&Wp[(size_t)(kg0 + bg[u]) * DD + n0 + bn[u]],
                    smem + 16384 + (size_t)(wv * 4 + u) * 1024);
        }
        __syncthreads();

        #pragma unroll
        for (int kk = 0; kk < 2; ++kk) {
            bf16x8 fa[4], fb[4];
            #pragma unroll
            for (int mi = 0; mi < 4; ++mi) {
                const int row = wr * 64 + mi * 16 + l15;
                fa[mi] = As[row][(kk * 4 + quad) ^ (row & 7)];
            }
            #pragma unroll
            for (int ni = 0; ni < 4; ++ni)
                fb[ni] = Bs[kk * 4 + quad][wc * 64 + ni * 16 + l15];
            #pragma unroll
            for (int mi = 0; mi < 4; ++mi)
                #pragma unroll
                for (int ni = 0; ni < 4; ++ni)
                    acc[mi][ni] = __builtin_amdgcn_mfma_f32_16x16x32_bf16(
                        fa[mi], fb[ni], acc[mi][ni], 0, 0, 0);
        }
    }

    if (z < 2) {
        bf16_t* C = (z == 0) ? C0 : C1;
        const float osc = (z == 0) ? SCL : 1.0f;   // pre-scale Q for exp2-domain softmax
        #pragma unroll
        for (int ni = 0; ni < 4; ++ni) {
            const int col = n0 + wc * 64 + ni * 16 + l15;
            const float bv = bias[col];
            #pragma unroll
            for (int mi = 0; mi < 4; ++mi)
                #pragma unroll
                for (int r = 0; r < 4; ++r) {
                    const int row = m0 + wr * 64 + mi * 16 + quad * 4 + r;
                    C[(size_t)row * DD + col] = f2bf((acc[mi][ni][r] + bv) * osc);
                }
        }
    } else {
        unsigned short (*T)[136] = reinterpret_cast<unsigned short(*)[136]>(smem);
        __syncthreads();
        #pragma unroll
        for (int ni = 0; ni < 4; ++ni) {
            const int cl = wc * 64 + ni * 16 + l15;
            const float bv = bias[n0 + cl];
            #pragma unroll
            for (int mi = 0; mi < 4; ++mi) {
                const int rl = wr * 64 + mi * 16 + quad * 4;
                uint2 pk;
                pk.x = pack_bf2(acc[mi][ni][0] + bv, acc[mi][ni][1] + bv);
                pk.y = pack_bf2(acc[mi][ni][2] + bv, acc[mi][ni][3] + bv);
                *reinterpret_cast<uint2*>(&T[cl][rl]) = pk;
            }
        }
        __syncthreads();
        const int b = m0 >> 11, s0 = m0 & 2047, h0 = n0 >> 6;
        #pragma unroll
        for (int u = 0; u < 8; ++u) {
            const int c = u * 256 + tid;
            const int s8 = c & 15, nl = c >> 4;
            const bf16x8 v = *reinterpret_cast<const bf16x8*>(&T[nl][s8 * 8]);
            const int bh = b * 16 + h0 + (nl >> 6), d = nl & 63;
            *reinterpret_cast<bf16x8*>(
                &Vt[((size_t)bh * 64 + d) * SS + s0 + s8 * 8]) = v;
        }
    }
}

// ---------- output GEMM: 128x64 tile, BK=64, fp32 out; 512 blocks = 2/CU ----------
__global__ __launch_bounds__(256)
void gemm_out(const bf16_t* __restrict__ A, const bf16x8* __restrict__ Wp,
              const float* __restrict__ bias, float* __restrict__ C) {
    __shared__ bf16x8 As[128][8];   // swz c^(r&7)
    __shared__ bf16x8 Bs[8][64];

    const int tid = threadIdx.x;
    const int ln = tid & 63, wv = tid >> 6;
    const int quad = ln >> 4, l15 = ln & 15;
    const int wr = wv >> 1, wc = wv & 1;
    const int m0 = blockIdx.y * 128;
    const int n0 = blockIdx.x * 64;

    int arow[4], acl[4], bkg[2], bn[2];
    #pragma unroll
    for (int u = 0; u < 4; ++u) {
        const int S = (wv * 4 + u) * 64 + ln;
        arow[u] = S >> 3; acl[u] = (S & 7) ^ (arow[u] & 7);
    }
    #pragma unroll
    for (int u = 0; u < 2; ++u) {
        const int S = (wv * 2 + u) * 64 + ln;
        bkg[u] = S >> 6; bn[u] = S & 63;
    }

    f32x4 acc[4][2];
    #pragma unroll
    for (int i = 0; i < 4; ++i)
        #pragma unroll
        for (int j = 0; j < 2; ++j) acc[i][j] = (f32x4){0.f, 0.f, 0.f, 0.f};

    for (int k0 = 0; k0 < DD; k0 += 64) {
        __syncthreads();
        const int kg0 = k0 >> 3;
        #pragma unroll
        for (int u = 0; u < 4; ++u)
            gload16(&A[(size_t)(m0 + arow[u]) * DD + k0 + acl[u] * 8],
                    (char*)&As[0][0] + (size_t)(wv * 4 + u) * 1024);
        #pragma unroll
        for (int u = 0; u < 2; ++u)
            gload16(&Wp[(size_t)(kg0 + bkg[u]) * DD + n0 + bn[u]],
                    (char*)&Bs[0][0] + (size_t)(wv * 2 + u) * 1024);
        __syncthreads();

        #pragma unroll
        for (int kk = 0; kk < 2; ++kk) {
            bf16x8 fa[4], fb[2];
            #pragma unroll
            for (int mi = 0; mi < 4; ++mi) {
                const int row = wr * 64 + mi * 16 + l15;
                fa[mi] = As[row][(kk * 4 + quad) ^ (row & 7)];
            }
            #pragma unroll
            for (int ni = 0; ni < 2; ++ni)
                fb[ni] = Bs[kk * 4 + quad][wc * 32 + ni * 16 + l15];
            #pragma unroll
            for (int mi = 0; mi < 4; ++mi)
                #pragma unroll
                for (int ni = 0; ni < 2; ++ni)
                    acc[mi][ni] = __builtin_amdgcn_mfma_f32_16x16x32_bf16(
                        fa[mi], fb[ni], acc[mi][ni], 0, 0, 0);
        }
    }

    #pragma unroll
    for (int ni = 0; ni < 2; ++ni) {
        const int col = n0 + wc * 32 + ni * 16 + l15;
        const float bv = bias[col];
        #pragma unroll
        for (int mi = 0; mi < 4; ++mi)
            #pragma unroll
            for (int r = 0; r < 4; ++r) {
                const int row = m0 + wr * 64 + mi * 16 + quad * 4 + r;
                C[(size_t)row * DD + col] = acc[mi][ni][r] + bv;
            }
    }
}

// ---------- MFMA flash attention: equal-work wrapped q-tile pairs ----------
// Block (bh, j) processes q-tiles j AND 31-j sequentially: (j+1)+(32-j) = 33
// k-tiles for EVERY block -> 512 identical blocks, 2/CU, 8 waves always
// resident (no concurrency collapse). LDS K/V staging shared by 4 waves;
// S^T = K Q'^T (Q pre-scaled by SCL); fixed-max exp2; O^T = V^T P^T;
// l via ones-MFMA; conflict-free swizzled Ps.
__global__ __launch_bounds__(256)
void attn_mfma(const bf16_t* __restrict__ Q, const bf16_t* __restrict__ Kg,
               const bf16_t* __restrict__ Vt, bf16_t* __restrict__ Ctx) {
    __shared__ bf16x8 Ks[64][8];              // [key][d-chunks], swz c^(row&7), 8 KB
    __shared__ bf16x8 Vs[64][8];              // [d][key-chunks], swz, 8 KB
    __shared__ unsigned short Ps[4][16][68];  // per-wave P^T [q][key], 8.7 KB

    const int tid = threadIdx.x;
    const int ln = tid & 63, w = tid >> 6;
    const int quad = ln >> 4, l15 = ln & 15;
    const int bh = blockIdx.x;
    const int b = bh >> 4, h = bh & 15;
    const size_t rowbase = (size_t)b * SS;
    const int col0 = h * 64;

    // staging geometry: 4 gload16 per wave per tile (K 2, V 2)
    const int krow0 = w * 16 + (ln >> 3);
    const int krow1 = krow0 + 8;
    const int kc0 = (ln & 7) ^ (krow0 & 7);
    const int kc1 = (ln & 7) ^ (krow1 & 7);
    char* const ksb = (char*)&Ks[0][0] + w * 2048;
    char* const vsb = (char*)&Vs[0][0] + w * 2048;

    bf16x8 vone;
    #pragma unroll
    for (int i = 0; i < 8; ++i) vone[i] = (bf16_t)1.0f;

    const int swz = l15 & 7;
    unsigned short* const psw = &Ps[w][l15][0];

    #pragma unroll 1
    for (int ph = 0; ph < 2; ++ph) {
        const int qt = ph ? (31 - (int)blockIdx.y) : (int)blockIdx.y;

        // Q fragments (pre-scaled by SCL at QKV epilogue)
        bf16x8 fq[2];
        {
            const int qrow = qt * 64 + w * 16 + l15;
            #pragma unroll
            for (int kk = 0; kk < 2; ++kk)
                fq[kk] = *reinterpret_cast<const bf16x8*>(
                    &Q[(rowbase + qrow) * DD + col0 + kk * 32 + quad * 8]);
        }

        f32x4 acc_o[4];
        #pragma unroll
        for (int i = 0; i < 4; ++i) acc_o[i] = (f32x4){0.f, 0.f, 0.f, 0.f};
        f32x4 acc_l = (f32x4){0.f, 0.f, 0.f, 0.f};

        #pragma unroll 1
        for (int kt = 0; kt <= qt; ++kt) {
            __syncthreads();   // previous tile's LDS reads complete
            gload16(&Kg[(rowbase + kt * 64 + krow0) * DD + col0 + kc0 * 8], ksb);
            gload16(&Kg[(rowbase + kt * 64 + krow1) * DD + col0 + kc1 * 8], ksb + 1024);
            gload16(&Vt[((size_t)bh * 64 + krow0) * SS + kt * 64 + kc0 * 8], vsb);
            gload16(&Vt[((size_t)bh * 64 + krow1) * SS + kt * 64 + kc1 * 8], vsb + 1024);
            __syncthreads();   // staging complete

            const bool diag = (kt == qt);
            // S^T = K Q'^T ; C layout: row=key=ni*16+quad*4+r, col=q=l15
            #pragma unroll
            for (int ni = 0; ni < 4; ++ni) {
                const int slot = ni * 4 + quad;
                unsigned short* pdst = psw + (((slot >> 1) ^ swz) * 8 + (slot & 1) * 4);
                if (diag && ni > w) {
                    *reinterpret_cast<uint2*>(pdst) = (uint2){0u, 0u};
                    continue;
                }
                f32x4 st = (f32x4){0.f, 0.f, 0.f, 0.f};
                const int krow = ni * 16 + l15;
                st = __builtin_amdgcn_mfma_f32_16x16x32_bf16(
                    Ks[krow][quad ^ (krow & 7)], fq[0], st, 0, 0, 0);
                st = __builtin_amdgcn_mfma_f32_16x16x32_bf16(
                    Ks[krow][(4 + quad) ^ (krow & 7)], fq[1], st, 0, 0, 0);
                float p[4];
                #pragma unroll
                for (int r = 0; r < 4; ++r) {
                    p[r] = __builtin_amdgcn_exp2f(st[r] - FM);
                    if (diag && ni == w && (quad * 4 + r) > l15) p[r] = 0.f;
                }
                uint2 pk;
                pk.x = pack_bf2(p[0], p[1]);
                pk.y = pack_bf2(p[2], p[3]);
                *reinterpret_cast<uint2*>(pdst) = pk;
            }

            // O^T += V^T P^T ; l += ones * P^T (lane's q = l15 -> direct l)
            #pragma unroll
            for (int kk = 0; kk < 2; ++kk) {
                const bf16x8 fp = *reinterpret_cast<const bf16x8*>(
                    psw + ((kk * 4 + quad) ^ swz) * 8);
                acc_l = __builtin_amdgcn_mfma_f32_16x16x32_bf16(vone, fp, acc_l, 0, 0, 0);
                #pragma unroll
                for (int nd = 0; nd < 4; ++nd) {
                    const int vrow = nd * 16 + l15;
                    acc_o[nd] = __builtin_amdgcn_mfma_f32_16x16x32_bf16(
                        Vs[vrow][(kk * 4 + quad) ^ (vrow & 7)], fp, acc_o[nd], 0, 0, 0);
                }
            }
        }

        // epilogue: lane holds one q (=l15), 16 d values
        const float inv = 1.f / acc_l[0];
        const size_t orow = (rowbase + qt * 64 + w * 16 + l15) * DD + col0;
        #pragma unroll
        for (int nd = 0; nd < 4; ++nd) {
            uint2 ov;
            ov.x = pack_bf2(acc_o[nd][0] * inv, acc_o[nd][1] * inv);
            ov.y = pack_bf2(acc_o[nd][2] * inv, acc_o[nd][3] * inv);
            *reinterpret_cast<uint2*>(&Ctx[orow + nd * 16 + quad * 4]) = ov;
        }
    }
}

extern "C" void kernel_launch(void* const* d_in, const int* in_sizes, int n_in,
                              void* d_out, int out_size, void* d_ws, size_t ws_size,
                              hipStream_t stream) {
    const float* x  = (const float*)d_in[0];
    const float* Wq = (const float*)d_in[1];
    const float* bq = (const float*)d_in[2];
    const float* Wk = (const float*)d_in[3];
    const float* bk = (const float*)d_in[4];
    const float* Wv = (const float*)d_in[5];
    const float* bv = (const float*)d_in[6];
    const float* Wo = (const float*)d_in[7];
    const float* bo = (const float*)d_in[8];
    float* out = (float*)d_out;

    const size_t M = (size_t)BB * SS;        // 4096
    const size_t mat = M * DD;               // 4M elements
    const size_t wsz = (size_t)DD * DD;

    bf16_t* ws = (bf16_t*)d_ws;
    bf16_t* xb   = ws;                       // 4M
    bf16_t* Wqp  = ws + mat;                 // 1M each
    bf16_t* Wkp  = Wqp + wsz;
    bf16_t* Wvp  = Wkp + wsz;
    bf16_t* Wop  = Wvp + wsz;
    bf16_t* Qb   = Wop + wsz;                // 4M
    bf16_t* Kb   = Qb + mat;                 // 4M
    bf16_t* Vtb  = Kb + mat;                 // 4M
    bf16_t* Ctxb = Vtb + mat;                // 4M -> 48 MB total

    dim3 blk(256);
    hipLaunchKernelGGL(prep_kernel, dim3(2560), blk, 0, stream,
                       x, xb, Wq, Wk, Wv, Wo,
                       (bf16x8*)Wqp, (bf16x8*)Wkp, (bf16x8*)Wvp, (bf16x8*)Wop);

    hipLaunchKernelGGL(gemm_qkv, dim3(DD / 128, M / 128, 3), blk, 34816, stream,
                       xb, (const bf16x8*)Wqp, (const bf16x8*)Wkp, (const bf16x8*)Wvp,
                       bq, bk, bv, Qb, Kb, Vtb);

    hipLaunchKernelGGL(attn_mfma, dim3(BB * HH, 16), blk, 0, stream,
                       Qb, Kb, Vtb, Ctxb);

    hipLaunchKernelGGL(gemm_out, dim3(DD / 64, M / 128), blk, 0, stream,
                       Ctxb, (const bf16x8*)Wop, bo, out);
}